// Round 1
// baseline (1429.516 us; speedup 1.0000x reference)
//
#include <hip/hip_runtime.h>
#include <stdint.h>

#define B_ROWS 64
#define D_DIM  2048
#define V_DIM  128000
#define N_TILE 128
#define NBLK   (V_DIM / N_TILE)   /* 1000 */
#define KCH    (D_DIM / 32)       /* 64   */

typedef float  f32x4  __attribute__((ext_vector_type(4)));
typedef __bf16 bf16x8 __attribute__((ext_vector_type(8)));

/* ---------------- phase 0: gather rows + fp32 -> (hi,lo) bf16 split,
   stored pre-swizzled in MFMA A-fragment order:
   element (m,k): c=k>>5, t=m>>4, quad=(k>>3)&3, j=k&7, lane=quad*16+(m&15)
   offset = ((c*4+t)*64 + lane)*8 + j                                    */
__global__ void prep_A(const float* __restrict__ hs, const int* __restrict__ idx,
                       __bf16* __restrict__ Ah, __bf16* __restrict__ Al)
{
    const int b   = blockIdx.x;    // 0..63
    const int tid = threadIdx.x;   // 0..255, covers k = tid*8 .. +7
    const int row = idx[b];
    const int k0  = tid * 8;
    const float* src = hs + (long)row * D_DIM + k0;
    const int c    = tid >> 2;
    const int quad = tid & 3;
    const int t    = b >> 4;
    const int lane = quad * 16 + (b & 15);
    const long off = ((long)(c * 4 + t) * 64 + lane) * 8;
    bf16x8 vh, vl;
#pragma unroll
    for (int j = 0; j < 8; j++) {
        float x = src[j];
        __bf16 h = (__bf16)x;              // RNE
        vh[j] = h;
        vl[j] = (__bf16)(x - (float)h);    // exact residual, then RNE
    }
    *(bf16x8*)(Ah + off) = vh;
    *(bf16x8*)(Al + off) = vl;
}

/* ---------------- main: 64 x V split-bf16 GEMM + fused tile reductions ----
   grid = 1000 blocks of 256 (4 waves). Wave w owns weight rows
   v0+w*32 .. +31. W is loaded DIRECTLY to registers in B-fragment order
   (lane reads 8 contiguous K elems of its own output row) -- no LDS, no
   global_load_lds, so there is never a vmcnt(0) drain in the K loop.
   A-fragments and W fp32 registers are ping-pong double-buffered: loads
   for chunk c+1 issue before compute of chunk c -> compiler emits counted
   vmcnt waits, prefetch stays in flight across the whole loop.
   Split/MFMA sequence is bit-identical to the previous LDS version.      */
__global__ void __launch_bounds__(256)
gemm_sample(const float* __restrict__ W,
            const __bf16* __restrict__ Ah,
            const __bf16* __restrict__ Al,
            const float* __restrict__ temp,
            const float* __restrict__ gum,
            f32x4* __restrict__ partA,
            float* __restrict__ partB)
{
    __shared__ float smem[8256];          // 64 x 129 logits tile (epilogue only)
    const int tid  = threadIdx.x;
    const int wid  = tid >> 6;
    const int lane = tid & 63;
    const int v0   = blockIdx.x * N_TILE;

    const int r0 = lane & 15;             // output col within 16-tile
    const int q  = lane >> 4;             // k-subgroup 0..3

    // B-fragment global pointers: lane holds row (v0+wid*32+u*16+r0),
    // k elements q*8 .. q*8+7 of each 32-wide chunk.
    const float*  pw0 = W + (long)(v0 + wid * 32 + r0) * D_DIM + q * 8;
    const float*  pw1 = pw0 + 16L * D_DIM;
    const __bf16* pah = Ah + lane * 8;
    const __bf16* pal = Al + lane * 8;

    f32x4 acc[4][2];
#pragma unroll
    for (int t = 0; t < 4; t++)
#pragma unroll
        for (int u = 0; u < 2; u++)
            acc[t][u] = (f32x4){0.f, 0.f, 0.f, 0.f};

    // ping-pong fragment buffers (named -> always statically indexed)
    bf16x8 ahA[4], alA[4], ahB[4], alB[4];
    f32x4 wA0a, wA0b, wA1a, wA1b;
    f32x4 wB0a, wB0b, wB1a, wB1b;

    auto load_chunk = [&](bf16x8 (&ah)[4], bf16x8 (&al)[4],
                          f32x4& w0a, f32x4& w0b, f32x4& w1a, f32x4& w1b) {
#pragma unroll
        for (int t = 0; t < 4; t++) {     // coalesced 1KB A-fragment loads (L2-hot)
            ah[t] = *(const bf16x8*)(pah + t * 512);
            al[t] = *(const bf16x8*)(pal + t * 512);
        }
        w0a = *(const f32x4*)(pw0);       // W[row_u0][c*32 + q*8 .. +3]
        w0b = *(const f32x4*)(pw0 + 4);   //            .. q*8+4 .. +7
        w1a = *(const f32x4*)(pw1);
        w1b = *(const f32x4*)(pw1 + 4);
        pah += 2048; pal += 2048;         // advance one 32-wide K chunk
        pw0 += 32;   pw1 += 32;
    };

    auto compute = [&](bf16x8 (&ah)[4], bf16x8 (&al)[4],
                       f32x4& w0a, f32x4& w0b, f32x4& w1a, f32x4& w1b) {
        {   // u = 0
            bf16x8 wh, wl;
#pragma unroll
            for (int j = 0; j < 4; j++) {
                float x = w0a[j]; __bf16 h = (__bf16)x;
                wh[j] = h; wl[j] = (__bf16)(x - (float)h);
            }
#pragma unroll
            for (int j = 0; j < 4; j++) {
                float x = w0b[j]; __bf16 h = (__bf16)x;
                wh[4 + j] = h; wl[4 + j] = (__bf16)(x - (float)h);
            }
#pragma unroll
            for (int t = 0; t < 4; t++) {   // 3-term split: hh + lh + hl
                acc[t][0] = __builtin_amdgcn_mfma_f32_16x16x32_bf16(ah[t], wh, acc[t][0], 0, 0, 0);
                acc[t][0] = __builtin_amdgcn_mfma_f32_16x16x32_bf16(al[t], wh, acc[t][0], 0, 0, 0);
                acc[t][0] = __builtin_amdgcn_mfma_f32_16x16x32_bf16(ah[t], wl, acc[t][0], 0, 0, 0);
            }
        }
        {   // u = 1
            bf16x8 wh, wl;
#pragma unroll
            for (int j = 0; j < 4; j++) {
                float x = w1a[j]; __bf16 h = (__bf16)x;
                wh[j] = h; wl[j] = (__bf16)(x - (float)h);
            }
#pragma unroll
            for (int j = 0; j < 4; j++) {
                float x = w1b[j]; __bf16 h = (__bf16)x;
                wh[4 + j] = h; wl[4 + j] = (__bf16)(x - (float)h);
            }
#pragma unroll
            for (int t = 0; t < 4; t++) {
                acc[t][1] = __builtin_amdgcn_mfma_f32_16x16x32_bf16(ah[t], wh, acc[t][1], 0, 0, 0);
                acc[t][1] = __builtin_amdgcn_mfma_f32_16x16x32_bf16(al[t], wh, acc[t][1], 0, 0, 0);
                acc[t][1] = __builtin_amdgcn_mfma_f32_16x16x32_bf16(ah[t], wl, acc[t][1], 0, 0, 0);
            }
        }
    };

    load_chunk(ahA, alA, wA0a, wA0b, wA1a, wA1b);           // chunk 0
    for (int c = 0; c < KCH - 2; c += 2) {
        load_chunk(ahB, alB, wB0a, wB0b, wB1a, wB1b);       // chunk c+1 in flight
        compute   (ahA, alA, wA0a, wA0b, wA1a, wA1b);       // chunk c
        load_chunk(ahA, alA, wA0a, wA0b, wA1a, wA1b);       // chunk c+2 in flight
        compute   (ahB, alB, wB0a, wB0b, wB1a, wB1b);       // chunk c+1
    }
    load_chunk(ahB, alB, wB0a, wB0b, wB1a, wB1b);           // chunk 63
    compute   (ahA, alA, wA0a, wA0b, wA1a, wA1b);           // chunk 62
    compute   (ahB, alB, wB0a, wB0b, wB1a, wB1b);           // chunk 63

    // C/D layout: col = lane&15, row = quad*4 + reg   (raw, un-scaled logits)
#pragma unroll
    for (int t = 0; t < 4; t++)
#pragma unroll
        for (int u = 0; u < 2; u++)
#pragma unroll
            for (int r = 0; r < 4; r++) {
                int m = t * 16 + q * 4 + r;
                int n = wid * 32 + u * 16 + r0;
                smem[m * 129 + n] = acc[t][u][r];
            }
    __syncthreads();

    // tile reductions: 4 threads per logits row, stride-4 columns
    const int brow = tid >> 2;
    const int qq   = tid & 3;
    const float invT = 1.0f / temp[brow];
    const float* lrow = smem + brow * 129;
    const float* grow = gum + (long)brow * V_DIM + v0;

    float gmax = -INFINITY; int gidx = 0;
    float smax = -INFINITY; int sidx = 0;
#pragma unroll 8
    for (int i = 0; i < 32; i++) {
        int col = qq + 4 * i;
        float L = lrow[col];
        if (L > gmax) { gmax = L; gidx = col; }
        float s = L * invT + grow[col];
        if (s > smax) { smax = s; sidx = col; }
    }
#pragma unroll
    for (int d = 1; d < 4; d <<= 1) {      // combine the 4 threads of this row
        float og = __shfl_xor(gmax, d); int oi = __shfl_xor(gidx, d);
        if (og > gmax || (og == gmax && oi < gidx)) { gmax = og; gidx = oi; }
        float os = __shfl_xor(smax, d); int si = __shfl_xor(sidx, d);
        if (os > smax || (os == smax && si < sidx)) { smax = os; sidx = si; }
    }
    float lsum = 0.f;                       // tile LSE relative to gmax*invT
#pragma unroll 8
    for (int i = 0; i < 32; i++) {
        int col = qq + 4 * i;
        lsum += __expf((lrow[col] - gmax) * invT);
    }
    lsum += __shfl_xor(lsum, 1);
    lsum += __shfl_xor(lsum, 2);
    if (qq == 0) {
        f32x4 p;
        p[0] = gmax; p[1] = __int_as_float(v0 + gidx);
        p[2] = smax; p[3] = __int_as_float(v0 + sidx);
        partA[(long)brow * NBLK + blockIdx.x] = p;
        partB[(long)brow * NBLK + blockIdx.x] = lsum;
    }
}

/* ---------------- finalize: combine 1000 partials per row ---------------- */
__global__ void finalize(const f32x4* __restrict__ partA, const float* __restrict__ partB,
                         const float* __restrict__ temp, const int* __restrict__ gmask,
                         const float* __restrict__ gum, float* __restrict__ out)
{
    const int b = blockIdx.x;
    const int tid = threadIdx.x;
    const float invT = 1.0f / temp[b];
    float mg = -INFINITY; int ig = 0;
    float ms = -INFINITY; int is_ = 0;
    float mx = -INFINITY; float sm = 0.f;
    for (int i = tid; i < NBLK; i += 256) {
        f32x4 p = partA[(long)b * NBLK + i];
        float ls = partB[(long)b * NBLK + i];
        int vi = __float_as_int(p[1]);
        if (p[0] > mg || (p[0] == mg && vi < ig)) { mg = p[0]; ig = vi; }
        int si = __float_as_int(p[3]);
        if (p[2] > ms || (p[2] == ms && si < is_)) { ms = p[2]; is_ = si; }
        float m2 = p[0] * invT;                    // tile's scaled max
        if (m2 > mx) { sm = sm * __expf(mx - m2) + ls; mx = m2; }
        else         { sm = sm + ls * __expf(m2 - mx); }
    }
#pragma unroll
    for (int d = 1; d < 64; d <<= 1) {
        float og = __shfl_xor(mg, d); int oi = __shfl_xor(ig, d);
        if (og > mg || (og == mg && oi < ig)) { mg = og; ig = oi; }
        float os = __shfl_xor(ms, d); int si = __shfl_xor(is_, d);
        if (os > ms || (os == ms && si < is_)) { ms = os; is_ = si; }
        float omx = __shfl_xor(mx, d); float osm = __shfl_xor(sm, d);
        if (omx > mx) { sm = sm * __expf(mx - omx) + osm; mx = omx; }
        else          { sm = sm + osm * __expf(omx - mx); }
    }
    __shared__ float red[4][8];
    const int w = tid >> 6;
    if ((tid & 63) == 0) {
        red[w][0] = mg; red[w][1] = __int_as_float(ig);
        red[w][2] = ms; red[w][3] = __int_as_float(is_);
        red[w][4] = mx; red[w][5] = sm;
    }
    __syncthreads();
    if (tid == 0) {
#pragma unroll
        for (int w2 = 1; w2 < 4; w2++) {
            float og = red[w2][0]; int oi = __float_as_int(red[w2][1]);
            if (og > mg || (og == mg && oi < ig)) { mg = og; ig = oi; }
            float os = red[w2][2]; int si = __float_as_int(red[w2][3]);
            if (os > ms || (os == ms && si < is_)) { ms = os; is_ = si; }
            float omx = red[w2][4], osm = red[w2][5];
            if (omx > mx) { sm = sm * __expf(mx - omx) + osm; mx = omx; }
            else          { sm = sm + osm * __expf(omx - mx); }
        }
        float logZ = mx + logf(sm);
        int id; float lp;
        if (gmask[b] != 0) { id = ig; lp = mg * invT - logZ; }
        else { id = is_; lp = (ms - gum[(long)b * V_DIM + is_]) - logZ; }
        out[b] = (float)id;          // ids < 2^24: exact in fp32
        out[B_ROWS + b] = lp;
    }
}

extern "C" void kernel_launch(void* const* d_in, const int* in_sizes, int n_in,
                              void* d_out, int out_size, void* d_ws, size_t ws_size,
                              hipStream_t stream)
{
    (void)in_sizes; (void)n_in; (void)out_size; (void)ws_size;
    const float* hs   = (const float*)d_in[0];
    const float* W    = (const float*)d_in[1];
    const float* temp = (const float*)d_in[2];
    const float* gum  = (const float*)d_in[3];
    const int*   idx  = (const int*)d_in[4];
    const int*   mask = (const int*)d_in[5];
    float* out = (float*)d_out;

    char* ws = (char*)d_ws;
    __bf16* Ah   = (__bf16*)ws;                         // 256 KB
    __bf16* Al   = (__bf16*)(ws + 262144);              // 256 KB
    f32x4*  pA   = (f32x4*)(ws + 524288);               // 64*1000*16 = 1,024,000 B
    float*  pB   = (float*)(ws + 524288 + 1024000);     // 64*1000*4  =   256,000 B

    prep_A     <<<B_ROWS, 256, 0, stream>>>(hs, idx, Ah, Al);
    gemm_sample<<<NBLK,   256, 0, stream>>>(W, Ah, Al, temp, gum, pA, pB);
    finalize   <<<B_ROWS, 256, 0, stream>>>(pA, pB, temp, mask, gum, out);
}